// Round 4
// baseline (770.919 us; speedup 1.0000x reference)
//
#include <hip/hip_runtime.h>

// LSS view transform, chunked-gather formulation, (pix,d)-parallel binning.
// out[b,c,cell] = sum_{(pix,d)->cell} img[b,c,pix] * dp[b,d,pix]
// Pipeline: transpose img -> count per cell -> prefix scan -> fill (cell-bucketed
// entries) -> chunked segmented reduction (64 entries/block, atomics only at
// cell-segment boundaries).
// Round-4 change: count/fill are parallel over all B*D*H*W points (983k threads,
// 3840 blocks) instead of per-pixel serial d-loops (60 blocks, 2.5% occupancy,
// dependent atomic chains). Run-merging dropped: duplicate (cell,pix) entries
// merge for free inside the gather's cell accumulator.
constexpr int IMG_H = 48, IMG_W = 160;
constexpr int HW    = IMG_H * IMG_W;          // 7680
constexpr int BEV_H = 128, BEV_W = 128;
constexpr int NCELL = BEV_H * BEV_W;          // 16384 per batch
constexpr int C_DIM = 128, D_DIM = 64, B_DIM = 2;
constexpr int NCELL_TOT = B_DIM * NCELL;      // 32768
constexpr int NPIX_TOT  = B_DIM * HW;         // 15360
constexpr int NPTS      = NPIX_TOT * D_DIM;   // 983040
constexpr int MAX_ENTRIES = NPTS;
constexpr int CHUNK = 64;
constexpr float X_MIN = -51.2f, Y_MIN = -51.2f;
constexpr float RES_X = 102.4f / 128.0f;
constexpr float RES_Y = 102.4f / 128.0f;

// ---- ws layout (4-byte words), ~16.1 MB total ----
constexpr size_t WS_IMG_T   = 0;                                     // float[B*HW*C]
constexpr size_t WS_HIST    = WS_IMG_T + (size_t)B_DIM * HW * C_DIM; // int[32768]
constexpr size_t WS_OFFS    = WS_HIST + NCELL_TOT;                   // int[32769]
constexpr size_t WS_CURSOR  = WS_OFFS + NCELL_TOT + 3;               // int[32768]
constexpr size_t WS_EKEY    = WS_CURSOR + NCELL_TOT;                 // int[MAX_ENTRIES]
constexpr size_t WS_EW      = WS_EKEY + MAX_ENTRIES;                 // float[MAX_ENTRIES]

__device__ inline void make_ray(const float* __restrict__ K, int b, float gx, float gy,
                                float& rx, float& ry, float& rz) {
    const float* Kb = K + b * 9;
    const float a00 = Kb[0], a01 = Kb[1], a02 = Kb[2];
    const float a10 = Kb[3], a11 = Kb[4], a12 = Kb[5];
    const float a20 = Kb[6], a21 = Kb[7], a22 = Kb[8];
    const float det = a00 * (a11 * a22 - a12 * a21)
                    - a01 * (a10 * a22 - a12 * a20)
                    + a02 * (a10 * a21 - a11 * a20);
    const float inv = 1.0f / det;
    const float i00 =  (a11 * a22 - a12 * a21) * inv;
    const float i01 = -(a01 * a22 - a02 * a21) * inv;
    const float i02 =  (a01 * a12 - a02 * a11) * inv;
    const float i10 = -(a10 * a22 - a12 * a20) * inv;
    const float i11 =  (a00 * a22 - a02 * a20) * inv;
    const float i12 = -(a00 * a12 - a02 * a10) * inv;
    const float i20 =  (a10 * a21 - a11 * a20) * inv;
    const float i21 = -(a00 * a21 - a01 * a20) * inv;
    const float i22 =  (a00 * a11 - a01 * a10) * inv;
    rx = i00 * gx + i01 * gy + i02;
    ry = i10 * gx + i11 * gy + i12;
    rz = i20 * gx + i21 * gy + i22;
}

// Returns global cell id (b*NCELL + cell) or -1. tid = ((b*D + d)*HW + pix).
__device__ inline int point_gcell(int tid, const float* __restrict__ dv,
                                  const float* __restrict__ K,
                                  const float* __restrict__ T) {
    const int pix = tid % HW;
    const int bd  = tid / HW;
    const int d   = bd % D_DIM;
    const int b   = bd / D_DIM;
    const int h = pix / IMG_W, w = pix % IMG_W;
    float rx, ry, rz;
    make_ray(K, b, (float)w, (float)h, rx, ry, rz);
    const float* Tb = T + b * 16;
    const float dep = dv[d];                       // wave-uniform
    const float px = dep * rx, py = dep * ry, pz = dep * rz;
    const float x = Tb[0] * px + Tb[1] * py + Tb[2]  * pz + Tb[3];
    const float y = Tb[4] * px + Tb[5] * py + Tb[6]  * pz + Tb[7];
    const float z = Tb[8] * px + Tb[9] * py + Tb[10] * pz + Tb[11];
    const int bx = (int)((x - X_MIN) / RES_X);     // truncate-toward-zero == astype(int32)
    const int by = (int)((y - Y_MIN) / RES_Y);
    const bool valid = (bx >= 0) && (bx < BEV_W) && (by >= 0) && (by < BEV_H) && (z > 0.0f);
    return valid ? (b * NCELL + by * BEV_W + bx) : -1;
}

// ---- K1: tiled transpose img[b,c,pix] -> img_t[b,pix,c] ----
__global__ __launch_bounds__(256) void k_transpose(const float* __restrict__ img,
                                                   float* __restrict__ img_t) {
    __shared__ float tile[32][33];
    const int b = blockIdx.z;
    const int tx = threadIdx.x, ty = threadIdx.y;      // block (32, 8)
    const int pix0 = blockIdx.x * 32, c0 = blockIdx.y * 32;
    #pragma unroll
    for (int j = 0; j < 32; j += 8)
        tile[ty + j][tx] = img[((size_t)(b * C_DIM + c0 + ty + j)) * HW + pix0 + tx];
    __syncthreads();
    #pragma unroll
    for (int j = 0; j < 32; j += 8)
        img_t[((size_t)(b * HW + pix0 + ty + j)) * C_DIM + c0 + tx] = tile[tx][ty + j];
}

// ---- K2: count points per cell. One thread per (b,d,pix). ----
__global__ __launch_bounds__(256) void k_count(const float* __restrict__ dv,
                                               const float* __restrict__ K,
                                               const float* __restrict__ T,
                                               int* __restrict__ hist) {
    const int tid = blockIdx.x * 256 + threadIdx.x;   // < NPTS (exact grid)
    const int gcell = point_gcell(tid, dv, K, T);
    if (gcell >= 0) atomicAdd(&hist[gcell], 1);
}

// ---- K3: exclusive prefix scan over hist[32768] -> offs[32769], cursor ----
__global__ __launch_bounds__(1024) void k_scan(const int* __restrict__ hist,
                                               int* __restrict__ offs,
                                               int* __restrict__ cursor) {
    __shared__ int lds[1024];
    const int t = threadIdx.x;
    int h[32];
    int s = 0;
    const int base = t * 32;
    #pragma unroll
    for (int k = 0; k < 32; ++k) { h[k] = hist[base + k]; s += h[k]; }
    lds[t] = s;
    __syncthreads();
    for (int off = 1; off < 1024; off <<= 1) {
        int v = (t >= off) ? lds[t - off] : 0;
        __syncthreads();
        lds[t] += v;
        __syncthreads();
    }
    int run = lds[t] - s;   // exclusive base for this thread's chunk
    #pragma unroll
    for (int k = 0; k < 32; ++k) {
        offs[base + k] = run;
        cursor[base + k] = run;
        run += h[k];
    }
    if (t == 1023) offs[NCELL_TOT] = lds[1023];
}

// ---- K4: fill cell-bucketed entries: key = (gcell<<13)|pix, weight = dp ----
__global__ __launch_bounds__(256) void k_fill(const float* __restrict__ dp,
                                              const float* __restrict__ dv,
                                              const float* __restrict__ K,
                                              const float* __restrict__ T,
                                              int* __restrict__ cursor,
                                              int* __restrict__ ekey,
                                              float* __restrict__ ew) {
    const int tid = blockIdx.x * 256 + threadIdx.x;   // < NPTS (exact grid)
    const int gcell = point_gcell(tid, dv, K, T);
    if (gcell < 0) return;
    const float p = dp[tid];                          // tid == ((b*D+d)*HW+pix): coalesced
    const int pix = tid % HW;
    const int slot = atomicAdd(&cursor[gcell], 1);
    ekey[slot] = (gcell << 13) | pix;
    ew[slot] = p;
}

// ---- K5: chunked segmented reduction. Block = 64 entries, thread = channel. ----
__global__ __launch_bounds__(128) void k_chunk_gather(
    const float* __restrict__ img_t,
    const int* __restrict__ offs,     // offs[NCELL_TOT] = total entry count
    const int* __restrict__ ekey,
    const float* __restrict__ ew,
    float* __restrict__ out)
{
    const int total = offs[NCELL_TOT];
    const int base = blockIdx.x * CHUNK;
    if (base >= total) return;

    __shared__ int   s_key[CHUNK];
    __shared__ float s_w[CHUNK];
    if (threadIdx.x < CHUNK) {
        const int i = threadIdx.x;
        const int idx = min(base + i, total - 1);
        s_key[i] = ekey[idx];                                   // pad = dup of last key
        s_w[i]   = (base + i < total) ? ew[base + i] : 0.0f;    // pad weight 0 -> no-op
    }
    __syncthreads();

    const int c = threadIdx.x;
    int prev_gcell = s_key[0] >> 13;
    float acc = 0.0f;
    #pragma unroll 8
    for (int k = 0; k < CHUNK; ++k) {                // static trip count -> pipelined
        const int key = s_key[k];                    // LDS broadcast (wave-uniform)
        const int gcell = key >> 13;
        const int pix = key & 8191;
        const int b = gcell >> 14;
        const float v = img_t[((size_t)(b * HW + pix)) * C_DIM + c] * s_w[k];
        if (gcell != prev_gcell) {                   // wave-uniform branch
            const int pb = prev_gcell >> 14, pc = prev_gcell & (NCELL - 1);
            atomicAdd(&out[((size_t)(pb * C_DIM + c)) * NCELL + pc], acc);
            acc = 0.0f;
            prev_gcell = gcell;
        }
        acc += v;
    }
    const int pb = prev_gcell >> 14, pc = prev_gcell & (NCELL - 1);
    atomicAdd(&out[((size_t)(pb * C_DIM + c)) * NCELL + pc], acc);
}

extern "C" void kernel_launch(void* const* d_in, const int* in_sizes, int n_in,
                              void* d_out, int out_size, void* d_ws, size_t ws_size,
                              hipStream_t stream) {
    const float* img = (const float*)d_in[0];
    const float* dp  = (const float*)d_in[1];
    const float* dv  = (const float*)d_in[2];
    const float* K   = (const float*)d_in[3];
    const float* T   = (const float*)d_in[4];
    float* out = (float*)d_out;

    float* ws_f   = (float*)d_ws;
    float* img_t  = ws_f + WS_IMG_T;
    int*   hist   = (int*)d_ws + WS_HIST;
    int*   offs   = (int*)d_ws + WS_OFFS;
    int*   cursor = (int*)d_ws + WS_CURSOR;
    int*   ekey   = (int*)d_ws + WS_EKEY;
    float* ew     = ws_f + WS_EW;

    hipMemsetAsync(hist, 0, NCELL_TOT * sizeof(int), stream);
    hipMemsetAsync(out, 0, (size_t)out_size * sizeof(float), stream);

    k_transpose<<<dim3(HW / 32, C_DIM / 32, B_DIM), dim3(32, 8), 0, stream>>>(img, img_t);
    k_count<<<NPTS / 256, 256, 0, stream>>>(dv, K, T, hist);
    k_scan<<<1, 1024, 0, stream>>>(hist, offs, cursor);
    k_fill<<<NPTS / 256, 256, 0, stream>>>(dp, dv, K, T, cursor, ekey, ew);
    k_chunk_gather<<<MAX_ENTRIES / CHUNK, 128, 0, stream>>>(img_t, offs, ekey, ew, out);
}

// Round 5
// 290.230 us; speedup vs baseline: 2.6562x; 2.6562x over previous
//
#include <hip/hip_runtime.h>

// LSS view transform, chunked-gather formulation, sharded binning.
// out[b,c,cell] = sum_{(pix,d)->cell} img[b,c,pix] * dp[b,d,pix]
// Pipeline: transpose img -> sharded count -> shard reduce -> prefix scan ->
// shard-base (in-place) -> fill (cell-bucketed entries) -> chunked segmented
// reduction (64 entries/block, atomics only at cell-segment boundaries).
// Round-5 change: hist/cursor sharded 16x (shard-major planes) to break the
// same-address atomic serialization on hot near-camera cells (round 4: ~2000
// increments to one address -> fill 312 us at 1% VALU). Weight stored as u16
// fixed-point (abs err <= 7.6e-6) to keep ws at the proven 16.12 MB footprint.
constexpr int IMG_H = 48, IMG_W = 160;
constexpr int HW    = IMG_H * IMG_W;          // 7680
constexpr int BEV_H = 128, BEV_W = 128;
constexpr int NCELL = BEV_H * BEV_W;          // 16384 per batch
constexpr int C_DIM = 128, D_DIM = 64, B_DIM = 2;
constexpr int NCELL_TOT = B_DIM * NCELL;      // 32768
constexpr int NPIX_TOT  = B_DIM * HW;         // 15360
constexpr int NPTS      = NPIX_TOT * D_DIM;   // 983040
constexpr int MAX_ENTRIES = NPTS;
constexpr int CHUNK = 64;
constexpr int NSHARD = 16;
constexpr float X_MIN = -51.2f, Y_MIN = -51.2f;
constexpr float RES_X = 102.4f / 128.0f;
constexpr float RES_Y = 102.4f / 128.0f;

// ---- ws layout (4-byte words), 16.12 MB total (== round-2 proven size) ----
constexpr size_t WS_IMG_T = 0;                                      // float[B*HW*C] 1966080
constexpr size_t WS_HIST2 = WS_IMG_T + (size_t)B_DIM * HW * C_DIM;  // int[NSHARD*32768] shard-major
constexpr size_t WS_HIST  = WS_HIST2 + (size_t)NSHARD * NCELL_TOT;  // int[32768]
constexpr size_t WS_OFFS  = WS_HIST + NCELL_TOT;                    // int[32769] (+3 pad)
constexpr size_t WS_EKEY  = WS_OFFS + NCELL_TOT + 4;                // int[MAX_ENTRIES]
constexpr size_t WS_EW16  = WS_EKEY + MAX_ENTRIES;                  // ushort[MAX_ENTRIES] = 491520 words

__device__ inline int point_shard(int tid) {
    return ((tid >> 2) + (tid >> 8)) & (NSHARD - 1);   // deterministic in tid
}

__device__ inline void make_ray(const float* __restrict__ K, int b, float gx, float gy,
                                float& rx, float& ry, float& rz) {
    const float* Kb = K + b * 9;
    const float a00 = Kb[0], a01 = Kb[1], a02 = Kb[2];
    const float a10 = Kb[3], a11 = Kb[4], a12 = Kb[5];
    const float a20 = Kb[6], a21 = Kb[7], a22 = Kb[8];
    const float det = a00 * (a11 * a22 - a12 * a21)
                    - a01 * (a10 * a22 - a12 * a20)
                    + a02 * (a10 * a21 - a11 * a20);
    const float inv = 1.0f / det;
    const float i00 =  (a11 * a22 - a12 * a21) * inv;
    const float i01 = -(a01 * a22 - a02 * a21) * inv;
    const float i02 =  (a01 * a12 - a02 * a11) * inv;
    const float i10 = -(a10 * a22 - a12 * a20) * inv;
    const float i11 =  (a00 * a22 - a02 * a20) * inv;
    const float i12 = -(a00 * a12 - a02 * a10) * inv;
    const float i20 =  (a10 * a21 - a11 * a20) * inv;
    const float i21 = -(a00 * a21 - a01 * a20) * inv;
    const float i22 =  (a00 * a11 - a01 * a10) * inv;
    rx = i00 * gx + i01 * gy + i02;
    ry = i10 * gx + i11 * gy + i12;
    rz = i20 * gx + i21 * gy + i22;
}

// Returns global cell id (b*NCELL + cell) or -1. tid = ((b*D + d)*HW + pix).
__device__ inline int point_gcell(int tid, const float* __restrict__ dv,
                                  const float* __restrict__ K,
                                  const float* __restrict__ T) {
    const int pix = tid % HW;
    const int bd  = tid / HW;
    const int d   = bd % D_DIM;
    const int b   = bd / D_DIM;
    const int h = pix / IMG_W, w = pix % IMG_W;
    float rx, ry, rz;
    make_ray(K, b, (float)w, (float)h, rx, ry, rz);
    const float* Tb = T + b * 16;
    const float dep = dv[d];                       // wave-uniform
    const float px = dep * rx, py = dep * ry, pz = dep * rz;
    const float x = Tb[0] * px + Tb[1] * py + Tb[2]  * pz + Tb[3];
    const float y = Tb[4] * px + Tb[5] * py + Tb[6]  * pz + Tb[7];
    const float z = Tb[8] * px + Tb[9] * py + Tb[10] * pz + Tb[11];
    const int bx = (int)((x - X_MIN) / RES_X);     // truncate-toward-zero == astype(int32)
    const int by = (int)((y - Y_MIN) / RES_Y);
    const bool valid = (bx >= 0) && (bx < BEV_W) && (by >= 0) && (by < BEV_H) && (z > 0.0f);
    return valid ? (b * NCELL + by * BEV_W + bx) : -1;
}

// ---- K1: tiled transpose img[b,c,pix] -> img_t[b,pix,c] ----
__global__ __launch_bounds__(256) void k_transpose(const float* __restrict__ img,
                                                   float* __restrict__ img_t) {
    __shared__ float tile[32][33];
    const int b = blockIdx.z;
    const int tx = threadIdx.x, ty = threadIdx.y;      // block (32, 8)
    const int pix0 = blockIdx.x * 32, c0 = blockIdx.y * 32;
    #pragma unroll
    for (int j = 0; j < 32; j += 8)
        tile[ty + j][tx] = img[((size_t)(b * C_DIM + c0 + ty + j)) * HW + pix0 + tx];
    __syncthreads();
    #pragma unroll
    for (int j = 0; j < 32; j += 8)
        img_t[((size_t)(b * HW + pix0 + ty + j)) * C_DIM + c0 + tx] = tile[tx][ty + j];
}

// ---- K2: sharded count. One thread per (b,d,pix). ----
__global__ __launch_bounds__(256) void k_count(const float* __restrict__ dv,
                                               const float* __restrict__ K,
                                               const float* __restrict__ T,
                                               int* __restrict__ hist2) {
    const int tid = blockIdx.x * 256 + threadIdx.x;   // < NPTS (exact grid)
    const int gcell = point_gcell(tid, dv, K, T);
    if (gcell >= 0)
        atomicAdd(&hist2[(size_t)point_shard(tid) * NCELL_TOT + gcell], 1);
}

// ---- K2b: reduce shards -> per-cell totals ----
__global__ __launch_bounds__(256) void k_reduce(const int* __restrict__ hist2,
                                                int* __restrict__ hist) {
    const int cell = blockIdx.x * 256 + threadIdx.x;  // 128 blocks exact
    int s = 0;
    #pragma unroll
    for (int sh = 0; sh < NSHARD; ++sh)
        s += hist2[(size_t)sh * NCELL_TOT + cell];
    hist[cell] = s;
}

// ---- K3: exclusive prefix scan over hist[32768] -> offs[32769] ----
__global__ __launch_bounds__(1024) void k_scan(const int* __restrict__ hist,
                                               int* __restrict__ offs) {
    __shared__ int lds[1024];
    const int t = threadIdx.x;
    int h[32];
    int s = 0;
    const int base = t * 32;
    #pragma unroll
    for (int k = 0; k < 32; ++k) { h[k] = hist[base + k]; s += h[k]; }
    lds[t] = s;
    __syncthreads();
    for (int off = 1; off < 1024; off <<= 1) {
        int v = (t >= off) ? lds[t - off] : 0;
        __syncthreads();
        lds[t] += v;
        __syncthreads();
    }
    int run = lds[t] - s;   // exclusive base for this thread's chunk
    #pragma unroll
    for (int k = 0; k < 32; ++k) {
        offs[base + k] = run;
        run += h[k];
    }
    if (t == 1023) offs[NCELL_TOT] = lds[1023];
}

// ---- K3b: per-cell shard prefix; hist2 becomes cursor bases in place ----
__global__ __launch_bounds__(256) void k_shardbase(int* __restrict__ hist2,
                                                   const int* __restrict__ offs) {
    const int cell = blockIdx.x * 256 + threadIdx.x;  // 128 blocks exact
    int run = offs[cell];
    #pragma unroll
    for (int sh = 0; sh < NSHARD; ++sh) {
        const size_t idx = (size_t)sh * NCELL_TOT + cell;
        const int cnt = hist2[idx];
        hist2[idx] = run;
        run += cnt;
    }
}

// ---- K4: fill cell-bucketed entries: key = (gcell<<13)|pix, weight u16 ----
__global__ __launch_bounds__(256) void k_fill(const float* __restrict__ dp,
                                              const float* __restrict__ dv,
                                              const float* __restrict__ K,
                                              const float* __restrict__ T,
                                              int* __restrict__ cursor2,   // = hist2 (bases)
                                              int* __restrict__ ekey,
                                              unsigned short* __restrict__ ew16) {
    const int tid = blockIdx.x * 256 + threadIdx.x;   // < NPTS (exact grid)
    const int gcell = point_gcell(tid, dv, K, T);
    if (gcell < 0) return;
    const float p = dp[tid];                          // tid == ((b*D+d)*HW+pix): coalesced
    const int slot = atomicAdd(&cursor2[(size_t)point_shard(tid) * NCELL_TOT + gcell], 1);
    ekey[slot] = (gcell << 13) | (tid % HW);
    ew16[slot] = (unsigned short)__float2uint_rn(p * 65535.0f);
}

// ---- K5: chunked segmented reduction. Block = 64 entries, thread = channel. ----
__global__ __launch_bounds__(128) void k_chunk_gather(
    const float* __restrict__ img_t,
    const int* __restrict__ offs,     // offs[NCELL_TOT] = total entry count
    const int* __restrict__ ekey,
    const unsigned short* __restrict__ ew16,
    float* __restrict__ out)
{
    const int total = offs[NCELL_TOT];
    const int base = blockIdx.x * CHUNK;
    if (base >= total) return;

    __shared__ int   s_key[CHUNK];
    __shared__ float s_w[CHUNK];
    if (threadIdx.x < CHUNK) {
        const int i = threadIdx.x;
        const int idx = min(base + i, total - 1);
        s_key[i] = ekey[idx];                                   // pad = dup of last key
        s_w[i]   = (base + i < total) ? (float)ew16[base + i] * (1.0f / 65535.0f)
                                      : 0.0f;                   // pad weight 0 -> no-op
    }
    __syncthreads();

    const int c = threadIdx.x;
    int prev_gcell = s_key[0] >> 13;
    float acc = 0.0f;
    #pragma unroll 8
    for (int k = 0; k < CHUNK; ++k) {                // static trip count -> pipelined
        const int key = s_key[k];                    // LDS broadcast (wave-uniform)
        const int gcell = key >> 13;
        const int pix = key & 8191;
        const int b = gcell >> 14;
        const float v = img_t[((size_t)(b * HW + pix)) * C_DIM + c] * s_w[k];
        if (gcell != prev_gcell) {                   // wave-uniform branch
            const int pb = prev_gcell >> 14, pc = prev_gcell & (NCELL - 1);
            atomicAdd(&out[((size_t)(pb * C_DIM + c)) * NCELL + pc], acc);
            acc = 0.0f;
            prev_gcell = gcell;
        }
        acc += v;
    }
    const int pb = prev_gcell >> 14, pc = prev_gcell & (NCELL - 1);
    atomicAdd(&out[((size_t)(pb * C_DIM + c)) * NCELL + pc], acc);
}

extern "C" void kernel_launch(void* const* d_in, const int* in_sizes, int n_in,
                              void* d_out, int out_size, void* d_ws, size_t ws_size,
                              hipStream_t stream) {
    const float* img = (const float*)d_in[0];
    const float* dp  = (const float*)d_in[1];
    const float* dv  = (const float*)d_in[2];
    const float* K   = (const float*)d_in[3];
    const float* T   = (const float*)d_in[4];
    float* out = (float*)d_out;

    float* ws_f   = (float*)d_ws;
    float* img_t  = ws_f + WS_IMG_T;
    int*   hist2  = (int*)d_ws + WS_HIST2;
    int*   hist   = (int*)d_ws + WS_HIST;
    int*   offs   = (int*)d_ws + WS_OFFS;
    int*   ekey   = (int*)d_ws + WS_EKEY;
    unsigned short* ew16 = (unsigned short*)((int*)d_ws + WS_EW16);

    hipMemsetAsync(hist2, 0, (size_t)NSHARD * NCELL_TOT * sizeof(int), stream);
    hipMemsetAsync(out, 0, (size_t)out_size * sizeof(float), stream);

    k_transpose<<<dim3(HW / 32, C_DIM / 32, B_DIM), dim3(32, 8), 0, stream>>>(img, img_t);
    k_count<<<NPTS / 256, 256, 0, stream>>>(dv, K, T, hist2);
    k_reduce<<<NCELL_TOT / 256, 256, 0, stream>>>(hist2, hist);
    k_scan<<<1, 1024, 0, stream>>>(hist, offs);
    k_shardbase<<<NCELL_TOT / 256, 256, 0, stream>>>(hist2, offs);
    k_fill<<<NPTS / 256, 256, 0, stream>>>(dp, dv, K, T, hist2, ekey, ew16);
    k_chunk_gather<<<MAX_ENTRIES / CHUNK, 128, 0, stream>>>(img_t, offs, ekey, ew16, out);
}